// Round 5
// baseline (844.457 us; speedup 1.0000x reference)
//
#include <hip/hip_runtime.h>
#include <hip/hip_bf16.h>
#include <cstdint>

typedef __attribute__((ext_vector_type(8))) short bf16x8;   // 8 bf16 (4 VGPRs)
typedef __attribute__((ext_vector_type(4))) float f32x4;    // MFMA C/D

#define BN_EPS 1e-5f

// ---------------------------------------------------------------------------
// prep1: fold BN1 + ring telescoping into V (box-feature weights), b1eff.
// ---------------------------------------------------------------------------
__global__ __launch_bounds__(256) void prep1_kernel(
    const float* __restrict__ W1, const float* __restrict__ cb1,
    const float* __restrict__ g1, const float* __restrict__ be1,
    const float* __restrict__ mu1, const float* __restrict__ va1,
    __hip_bfloat16* __restrict__ V, float* __restrict__ b1e)
{
  int o = blockIdx.x;
  int t = threadIdx.x;
  const float* wrow = W1 + (size_t)o * 1248;
  float acc = 0.f;
  for (int i = t; i < 1248; i += 256) {
    float s = g1[i] * rsqrtf(va1[i] + BN_EPS);
    float w = wrow[i];
    acc += w * (be1[i] - mu1[i] * s);
    float g = w * s;
    float gn = 0.f;
    if (i < 1152) {  // has a next-ring partner
      float sn = g1[i + 96] * rsqrtf(va1[i + 96] + BN_EPS);
      gn = wrow[i + 96] * sn;
    }
    V[(size_t)o * 1248 + i] = __float2bfloat16(g - gn);
  }
  for (int d = 32; d > 0; d >>= 1) acc += __shfl_down(acc, d);
  __shared__ float red[4];
  int lane = t & 63, wv = t >> 6;
  if (lane == 0) red[wv] = acc;
  __syncthreads();
  if (t == 0) b1e[o] = cb1[o] + red[0] + red[1] + red[2] + red[3];
}

// ---------------------------------------------------------------------------
// prep2: fold BN2 into W2eff, b2eff.
// ---------------------------------------------------------------------------
__global__ __launch_bounds__(256) void prep2_kernel(
    const float* __restrict__ W2, const float* __restrict__ cb2,
    const float* __restrict__ g2, const float* __restrict__ be2,
    const float* __restrict__ mu2, const float* __restrict__ va2,
    __hip_bfloat16* __restrict__ W2e, float* __restrict__ b2e)
{
  int o = blockIdx.x;
  int t = threadIdx.x;
  const float* wrow = W2 + (size_t)o * 512;
  float acc = 0.f;
  for (int j = t; j < 512; j += 256) {
    float s = g2[j] * rsqrtf(va2[j] + BN_EPS);
    float wv = wrow[j];
    acc += wv * (be2[j] - mu2[j] * s);
    W2e[(size_t)o * 512 + j] = __float2bfloat16(wv * s);
  }
  for (int d = 32; d > 0; d >>= 1) acc += __shfl_down(acc, d);
  __shared__ float red[4];
  int lane = t & 63, wv2 = t >> 6;
  if (lane == 0) red[wv2] = acc;
  __syncthreads();
  if (t == 0) b2e[o] = cb2[o] + red[0] + red[1] + red[2] + red[3];
}

// ---------------------------------------------------------------------------
// sat v2: one block per (b,c) plane. Exclusive SAT [129][132].
// float4 row scan (32 steps instead of 128), granule-XOR swizzle so both
// row (b128) and column (b32) passes are conflict-free.
// ---------------------------------------------------------------------------
__global__ __launch_bounds__(128) void sat_kernel(
    const float* __restrict__ x, float* __restrict__ SAT)
{
  int plane = blockIdx.x;
  const float* xp = x + (size_t)plane * 16384;
  __shared__ float tile[16384];   // [r][granule-swizzled]
  int t = threadIdx.x;
  // load as float4: 4096 tasks / 128 thr = 32 iters
  for (int i4 = t; i4 < 4096; i4 += 128) {
    int r = i4 >> 5;
    int g = i4 & 31;                       // granule of 4 floats
    float4 v = *(const float4*)(xp + (size_t)r * 128 + g * 4);
    *(float4*)(tile + r * 128 + ((g ^ (r & 31)) << 2)) = v;
  }
  __syncthreads();
  {  // row scan: thread = row, float4 granules with carry
    int r = t;
    float carry = 0.f;
    for (int g = 0; g < 32; ++g) {
      float* p = tile + r * 128 + ((g ^ (r & 31)) << 2);
      float4 v = *(float4*)p;
      float s0 = carry + v.x, s1 = s0 + v.y, s2 = s1 + v.z, s3 = s2 + v.w;
      float4 o; o.x = s0; o.y = s1; o.z = s2; o.w = s3;
      *(float4*)p = o;
      carry = s3;
    }
  }
  __syncthreads();
  // column scan + global write: thread = column
  float* Sg = SAT + (size_t)plane * 17028;  // 129*132
  Sg[t] = 0.f;                   // row 0, cols 0..127
  if (t < 4) Sg[128 + t] = 0.f;  // row 0, cols 128..131
  Sg[(t + 1) * 132] = 0.f;       // col 0, rows 1..128
  int gc = t >> 2, wc = t & 3;
  float run = 0.f;
  for (int r = 0; r < 128; ++r) {
    run += tile[r * 128 + ((gc ^ (r & 31)) << 2) + wc];
    Sg[(r + 1) * 132 + t + 1] = run;
  }
}

// ---------------------------------------------------------------------------
// fused1 v2: feat + gemm1 fused. One block per image row (bL,y): M=128 px,
// N=512, K=1248. Per ring j (2 barriers only):
//   [build As[128][104] bf16 for ALL 96 ch from E]  barrier
//   [3 MFMA sub-phases (96 MFMA/wave) + efill(j+1) overlapped]  barrier
// E[c][x] = S[y2][x]-S[y1][x] (fp32, float4 L2 reads). Dynamic LDS 77.3KB
// (E 50688 + As 26624) -> 2 blocks/CU. Epilogue stages Y1 through LDS so
// global stores are 512B-contiguous per pixel row.
// ---------------------------------------------------------------------------
__global__ __launch_bounds__(512, 4) void fused1_kernel(
    const float* __restrict__ SAT, const __hip_bfloat16* __restrict__ V,
    const float* __restrict__ b1e, __hip_bfloat16* __restrict__ Y1, int nb)
{
  extern __shared__ __align__(16) char smem[];
  float* E = (float*)smem;                                   // 96*132 fp32
  __hip_bfloat16* As = (__hip_bfloat16*)(smem + 50688);      // [128][104]

  int blk = blockIdx.x;
  int rows_per_xcd = (nb * 128) >> 3;
  int r = (blk & 7) * rows_per_xcd + (blk >> 3);
  int bL = r >> 7, y = r & 127;

  int t = threadIdx.x;
  int lane = t & 63, wv = t >> 6;              // wv 0..7: 64-col N-slab
  int lr = lane & 15, quad = lane >> 4;
  int px = t & 127;                            // build pixel
  int bg = t >> 7;                             // build granule base 0..3

  const float* Sb = SAT + (size_t)bL * 96 * 17028;

  f32x4 acc[8][4];
#pragma unroll
  for (int i = 0; i < 8; ++i)
#pragma unroll
    for (int jn = 0; jn < 4; ++jn) acc[i][jn] = (f32x4){0.f, 0.f, 0.f, 0.f};

  // E-fill for ring j: 96 ch x 33 float4 granules = 3168 tasks
  auto efill = [&](int j) {
    int y1 = (y - j < 0) ? 0 : (y - j);
    int y2 = ((y + j > 127) ? 127 : (y + j)) + 1;
    for (int idx = t; idx < 3168; idx += 512) {
      int cl = idx / 33;
      int ck = idx - cl * 33;
      const float* bp = Sb + (size_t)cl * 17028 + ck * 4;
      float4 a = *(const float4*)(bp + y2 * 132);
      float4 b = *(const float4*)(bp + y1 * 132);
      float4 d;
      d.x = a.x - b.x; d.y = a.y - b.y; d.z = a.z - b.z; d.w = a.w - b.w;
      *(float4*)(E + cl * 132 + ck * 4) = d;
    }
  };

  efill(0);
  __syncthreads();

  for (int j = 0; j < 13; ++j) {
    int x1 = (px - j < 0) ? 0 : (px - j);
    int x2 = ((px + j > 127) ? 127 : (px + j)) + 1;
    // build ALL 96 channels: 3 passes of (1 px, 8 ch)
#pragma unroll
    for (int pass = 0; pass < 3; ++pass) {
      int g = bg + pass * 4;                  // granule 0..11
      const float* Eb = E + g * 8 * 132;
      union { bf16x8 v; __hip_bfloat16 h[8]; } pk;
#pragma unroll
      for (int i = 0; i < 8; ++i)
        pk.h[i] = __float2bfloat16(Eb[i * 132 + x2] - Eb[i * 132 + x1]);
      *(bf16x8*)(As + px * 104 + g * 8) = pk.v;
    }
    __syncthreads();   // As ready; E(j) fully consumed

#pragma unroll
    for (int sub = 0; sub < 3; ++sub) {
      bf16x8 af[8], bfr[4];
#pragma unroll
      for (int i = 0; i < 8; ++i)
        af[i] = *(const bf16x8*)(As + (i * 16 + lr) * 104 + sub * 32 + quad * 8);
#pragma unroll
      for (int jn = 0; jn < 4; ++jn)
        bfr[jn] = *(const bf16x8*)(V + (size_t)(wv * 64 + jn * 16 + lr) * 1248
                                   + j * 96 + sub * 32 + quad * 8);
#pragma unroll
      for (int i = 0; i < 8; ++i)
#pragma unroll
        for (int jn = 0; jn < 4; ++jn)
          acc[i][jn] = __builtin_amdgcn_mfma_f32_16x16x32_bf16(af[i], bfr[jn], acc[i][jn], 0, 0, 0);
      if (sub == 0 && j < 12) efill(j + 1);   // hidden under subs 1,2 MFMA
    }
    __syncthreads();   // E(j+1) ready; As consumed
  }

  // ---- epilogue: bias+relu, stage Y1 halves through LDS, coalesced store ----
  size_t mrow = (size_t)bL * 16384 + (size_t)y * 128;
  __hip_bfloat16* Yst = (__hip_bfloat16*)smem;   // 128*256*2 = 64KB <= 77.3KB
#pragma unroll
  for (int half = 0; half < 2; ++half) {
    if ((wv >> 2) == half) {
      __hip_bfloat16* st = Yst + (size_t)(wv & 3) * (128 * 64);
#pragma unroll
      for (int jn = 0; jn < 4; ++jn) {
        int n = wv * 64 + jn * 16 + lr;
        float bias = b1e[n];
#pragma unroll
        for (int i = 0; i < 8; ++i) {
#pragma unroll
          for (int rr = 0; rr < 4; ++rr) {
            int m = i * 16 + quad * 4 + rr;
            float z = acc[i][jn][rr] + bias;
            z = z > 0.f ? z : 0.f;
            st[m * 64 + jn * 16 + lr] = __float2bfloat16(z);
          }
        }
      }
    }
    __syncthreads();
    // copy 128 px x 256 n: 4096 b128 chunks = 512 thr x 8
#pragma unroll
    for (int it = 0; it < 8; ++it) {
      int q = it * 512 + t;
      int p2 = q >> 5, ck = q & 31;
      uint4 v = *(uint4*)(Yst + (size_t)(ck >> 3) * (128 * 64) + p2 * 64 + (ck & 7) * 8);
      *(uint4*)(Y1 + (mrow + p2) * 512 + half * 256 + ck * 8) = v;
    }
    __syncthreads();
  }
}

// ---------------------------------------------------------------------------
// gemm2: out[b][o2][p] = W2e[o2][:] * Y1[pix][:] + b2e[o2]; C[o2][pixel]
// computed directly so NCHW stores are coalesced. LDS-free (W2e L2-hot).
// ---------------------------------------------------------------------------
__global__ __launch_bounds__(256) void gemm2_kernel(
    const __hip_bfloat16* __restrict__ Y1,   // [Mpix][512]
    const __hip_bfloat16* __restrict__ W2e,  // [96][512]
    const float* __restrict__ b2e,
    float* __restrict__ out, int b0)
{
  int lane = threadIdx.x & 63, wv = threadIdx.x >> 6;
  int lr = lane & 15, quad = lane >> 4;
  int pw = blockIdx.x * 256 + wv * 64;  // wave's pixel base

  f32x4 acc[6][4];
#pragma unroll
  for (int im = 0; im < 6; ++im)
#pragma unroll
    for (int jn = 0; jn < 4; ++jn) acc[im][jn] = (f32x4){0.f, 0.f, 0.f, 0.f};

  for (int k0 = 0; k0 < 512; k0 += 32) {
    bf16x8 bfrag[4], afrag[6];
#pragma unroll
    for (int jn = 0; jn < 4; ++jn)
      bfrag[jn] = *(const bf16x8*)(Y1 + (size_t)(pw + jn * 16 + lr) * 512 + k0 + quad * 8);
#pragma unroll
    for (int im = 0; im < 6; ++im)
      afrag[im] = *(const bf16x8*)(W2e + (size_t)(im * 16 + lr) * 512 + k0 + quad * 8);
#pragma unroll
    for (int im = 0; im < 6; ++im)
#pragma unroll
      for (int jn = 0; jn < 4; ++jn)
        acc[im][jn] = __builtin_amdgcn_mfma_f32_16x16x32_bf16(afrag[im], bfrag[jn], acc[im][jn], 0, 0, 0);
  }

#pragma unroll
  for (int im = 0; im < 6; ++im) {
#pragma unroll
    for (int r = 0; r < 4; ++r) {
      int o2 = im * 16 + quad * 4 + r;
      float bias = b2e[o2];
#pragma unroll
      for (int jn = 0; jn < 4; ++jn) {
        int p = pw + jn * 16 + lr;
        out[((size_t)(b0 + (p >> 14)) * 96 + o2) * 16384 + (p & 16383)] =
            acc[im][jn][r] + bias;
      }
    }
  }
}

// ---------------------------------------------------------------------------
extern "C" void kernel_launch(void* const* d_in, const int* in_sizes, int n_in,
                              void* d_out, int out_size, void* d_ws, size_t ws_size,
                              hipStream_t stream)
{
  const float* x   = (const float*)d_in[0];
  const float* g1  = (const float*)d_in[1];
  const float* be1 = (const float*)d_in[2];
  const float* mu1 = (const float*)d_in[3];
  const float* va1 = (const float*)d_in[4];
  const float* W1  = (const float*)d_in[5];
  const float* cb1 = (const float*)d_in[6];
  const float* g2  = (const float*)d_in[7];
  const float* be2 = (const float*)d_in[8];
  const float* mu2 = (const float*)d_in[9];
  const float* va2 = (const float*)d_in[10];
  const float* W2  = (const float*)d_in[11];
  const float* cb2 = (const float*)d_in[12];
  float* out = (float*)d_out;

  static bool attr_set = false;
  if (!attr_set) {
    hipFuncSetAttribute((const void*)fused1_kernel,
                        hipFuncAttributeMaxDynamicSharedMemorySize, 77312);
    attr_set = true;
  }

  char* w = (char*)d_ws;
  __hip_bfloat16* V   = (__hip_bfloat16*)w; w += (size_t)512 * 1248 * 2;
  __hip_bfloat16* W2e = (__hip_bfloat16*)w; w += (size_t)96 * 512 * 2;
  float* b1e = (float*)w; w += 2048;
  float* b2e = (float*)w; w += 512;
  size_t fixed = (size_t)(w - (char*)d_ws);

  const size_t satB = (size_t)96 * 17028 * 4;     // per-batch SAT bytes
  const size_t yB   = (size_t)16384 * 512 * 2;    // per-batch Y1 bytes
  int nb = (ws_size >= fixed + 4 * (satB + yB) + 4096) ? 4 : 1;

  float* SAT = (float*)w; w += (size_t)nb * satB;
  w = (char*)(((uintptr_t)w + 255) & ~(uintptr_t)255);
  __hip_bfloat16* Y1 = (__hip_bfloat16*)w;

  prep1_kernel<<<512, 256, 0, stream>>>(W1, cb1, g1, be1, mu1, va1, V, b1e);
  prep2_kernel<<<96, 256, 0, stream>>>(W2, cb2, g2, be2, mu2, va2, W2e, b2e);

  for (int b0 = 0; b0 < 4; b0 += nb) {
    sat_kernel<<<nb * 96, 128, 0, stream>>>(x + (size_t)b0 * 96 * 16384, SAT);
    fused1_kernel<<<nb * 128, 512, 77312, stream>>>(SAT, V, b1e, Y1, nb);
    gemm2_kernel<<<nb * 64, 256, 0, stream>>>(Y1, W2e, b2e, out, b0);
  }
}

// Round 6
// 309.707 us; speedup vs baseline: 2.7266x; 2.7266x over previous
//
#include <hip/hip_runtime.h>
#include <hip/hip_bf16.h>
#include <cstdint>

typedef __attribute__((ext_vector_type(8))) short bf16x8;   // 8 bf16 (4 VGPRs)
typedef __attribute__((ext_vector_type(4))) float f32x4;    // MFMA C/D

#define BN_EPS 1e-5f

// ---------------------------------------------------------------------------
// prep1: fold BN1 + ring telescoping into V (box-feature weights), b1eff.
// ---------------------------------------------------------------------------
__global__ __launch_bounds__(256) void prep1_kernel(
    const float* __restrict__ W1, const float* __restrict__ cb1,
    const float* __restrict__ g1, const float* __restrict__ be1,
    const float* __restrict__ mu1, const float* __restrict__ va1,
    __hip_bfloat16* __restrict__ V, float* __restrict__ b1e)
{
  int o = blockIdx.x;
  int t = threadIdx.x;
  const float* wrow = W1 + (size_t)o * 1248;
  float acc = 0.f;
  for (int i = t; i < 1248; i += 256) {
    float s = g1[i] * rsqrtf(va1[i] + BN_EPS);
    float w = wrow[i];
    acc += w * (be1[i] - mu1[i] * s);
    float g = w * s;
    float gn = 0.f;
    if (i < 1152) {  // has a next-ring partner
      float sn = g1[i + 96] * rsqrtf(va1[i + 96] + BN_EPS);
      gn = wrow[i + 96] * sn;
    }
    V[(size_t)o * 1248 + i] = __float2bfloat16(g - gn);
  }
  for (int d = 32; d > 0; d >>= 1) acc += __shfl_down(acc, d);
  __shared__ float red[4];
  int lane = t & 63, wv = t >> 6;
  if (lane == 0) red[wv] = acc;
  __syncthreads();
  if (t == 0) b1e[o] = cb1[o] + red[0] + red[1] + red[2] + red[3];
}

// ---------------------------------------------------------------------------
// prep2: fold BN2 into W2eff, b2eff.
// ---------------------------------------------------------------------------
__global__ __launch_bounds__(256) void prep2_kernel(
    const float* __restrict__ W2, const float* __restrict__ cb2,
    const float* __restrict__ g2, const float* __restrict__ be2,
    const float* __restrict__ mu2, const float* __restrict__ va2,
    __hip_bfloat16* __restrict__ W2e, float* __restrict__ b2e)
{
  int o = blockIdx.x;
  int t = threadIdx.x;
  const float* wrow = W2 + (size_t)o * 512;
  float acc = 0.f;
  for (int j = t; j < 512; j += 256) {
    float s = g2[j] * rsqrtf(va2[j] + BN_EPS);
    float wv = wrow[j];
    acc += wv * (be2[j] - mu2[j] * s);
    W2e[(size_t)o * 512 + j] = __float2bfloat16(wv * s);
  }
  for (int d = 32; d > 0; d >>= 1) acc += __shfl_down(acc, d);
  __shared__ float red[4];
  int lane = t & 63, wv2 = t >> 6;
  if (lane == 0) red[wv2] = acc;
  __syncthreads();
  if (t == 0) b2e[o] = cb2[o] + red[0] + red[1] + red[2] + red[3];
}

// ---------------------------------------------------------------------------
// sat v2: one block per (b,c) plane. Exclusive SAT [129][132].
// float4 row scan (32 steps instead of 128), granule-XOR swizzle so both
// row (b128) and column (b32) passes are conflict-free.
// ---------------------------------------------------------------------------
__global__ __launch_bounds__(128) void sat_kernel(
    const float* __restrict__ x, float* __restrict__ SAT)
{
  int plane = blockIdx.x;
  const float* xp = x + (size_t)plane * 16384;
  __shared__ float tile[16384];   // [r][granule-swizzled]
  int t = threadIdx.x;
  for (int i4 = t; i4 < 4096; i4 += 128) {
    int r = i4 >> 5;
    int g = i4 & 31;                       // granule of 4 floats
    float4 v = *(const float4*)(xp + (size_t)r * 128 + g * 4);
    *(float4*)(tile + r * 128 + ((g ^ (r & 31)) << 2)) = v;
  }
  __syncthreads();
  {  // row scan: thread = row, float4 granules with carry
    int r = t;
    float carry = 0.f;
    for (int g = 0; g < 32; ++g) {
      float* p = tile + r * 128 + ((g ^ (r & 31)) << 2);
      float4 v = *(float4*)p;
      float s0 = carry + v.x, s1 = s0 + v.y, s2 = s1 + v.z, s3 = s2 + v.w;
      float4 o; o.x = s0; o.y = s1; o.z = s2; o.w = s3;
      *(float4*)p = o;
      carry = s3;
    }
  }
  __syncthreads();
  float* Sg = SAT + (size_t)plane * 17028;  // 129*132
  Sg[t] = 0.f;                   // row 0, cols 0..127
  if (t < 4) Sg[128 + t] = 0.f;  // row 0, cols 128..131
  Sg[(t + 1) * 132] = 0.f;       // col 0, rows 1..128
  int gc = t >> 2, wc = t & 3;
  float run = 0.f;
  for (int r = 0; r < 128; ++r) {
    run += tile[r * 128 + ((gc ^ (r & 31)) << 2) + wc];
    Sg[(r + 1) * 132 + t + 1] = run;
  }
}

// ---------------------------------------------------------------------------
// fused1 v3: identical structure to v2, but __launch_bounds__(512,2).
// (v2's (512,4) capped regs at 128/wave -> the 128 accumulator VGPRs spilled
//  to scratch: 3.3 GB HBM traffic, 708 us. The acc array is the irreducible
//  live set; never bound below ~244.)
// ---------------------------------------------------------------------------
__global__ __launch_bounds__(512, 2) void fused1_kernel(
    const float* __restrict__ SAT, const __hip_bfloat16* __restrict__ V,
    const float* __restrict__ b1e, __hip_bfloat16* __restrict__ Y1, int nb)
{
  extern __shared__ __align__(16) char smem[];
  float* E = (float*)smem;                                   // 96*132 fp32
  __hip_bfloat16* As = (__hip_bfloat16*)(smem + 50688);      // [128][104]

  int blk = blockIdx.x;
  int rows_per_xcd = (nb * 128) >> 3;
  int r = (blk & 7) * rows_per_xcd + (blk >> 3);
  int bL = r >> 7, y = r & 127;

  int t = threadIdx.x;
  int lane = t & 63, wv = t >> 6;              // wv 0..7: 64-col N-slab
  int lr = lane & 15, quad = lane >> 4;
  int px = t & 127;                            // build pixel
  int bg = t >> 7;                             // build granule base 0..3

  const float* Sb = SAT + (size_t)bL * 96 * 17028;

  f32x4 acc[8][4];
#pragma unroll
  for (int i = 0; i < 8; ++i)
#pragma unroll
    for (int jn = 0; jn < 4; ++jn) acc[i][jn] = (f32x4){0.f, 0.f, 0.f, 0.f};

  // E-fill for ring j: 96 ch x 33 float4 granules = 3168 tasks
  auto efill = [&](int j) {
    int y1 = (y - j < 0) ? 0 : (y - j);
    int y2 = ((y + j > 127) ? 127 : (y + j)) + 1;
    for (int idx = t; idx < 3168; idx += 512) {
      int cl = idx / 33;
      int ck = idx - cl * 33;
      const float* bp = Sb + (size_t)cl * 17028 + ck * 4;
      float4 a = *(const float4*)(bp + y2 * 132);
      float4 b = *(const float4*)(bp + y1 * 132);
      float4 d;
      d.x = a.x - b.x; d.y = a.y - b.y; d.z = a.z - b.z; d.w = a.w - b.w;
      *(float4*)(E + cl * 132 + ck * 4) = d;
    }
  };

  efill(0);
  __syncthreads();

  for (int j = 0; j < 13; ++j) {
    int x1 = (px - j < 0) ? 0 : (px - j);
    int x2 = ((px + j > 127) ? 127 : (px + j)) + 1;
    // build ALL 96 channels: 3 passes of (1 px, 8 ch)
#pragma unroll
    for (int pass = 0; pass < 3; ++pass) {
      int g = bg + pass * 4;                  // granule 0..11
      const float* Eb = E + g * 8 * 132;
      union { bf16x8 v; __hip_bfloat16 h[8]; } pk;
#pragma unroll
      for (int i = 0; i < 8; ++i)
        pk.h[i] = __float2bfloat16(Eb[i * 132 + x2] - Eb[i * 132 + x1]);
      *(bf16x8*)(As + px * 104 + g * 8) = pk.v;
    }
    __syncthreads();   // As ready; E(j) fully consumed

#pragma unroll
    for (int sub = 0; sub < 3; ++sub) {
      bf16x8 af[8], bfr[4];
#pragma unroll
      for (int i = 0; i < 8; ++i)
        af[i] = *(const bf16x8*)(As + (i * 16 + lr) * 104 + sub * 32 + quad * 8);
#pragma unroll
      for (int jn = 0; jn < 4; ++jn)
        bfr[jn] = *(const bf16x8*)(V + (size_t)(wv * 64 + jn * 16 + lr) * 1248
                                   + j * 96 + sub * 32 + quad * 8);
#pragma unroll
      for (int i = 0; i < 8; ++i)
#pragma unroll
        for (int jn = 0; jn < 4; ++jn)
          acc[i][jn] = __builtin_amdgcn_mfma_f32_16x16x32_bf16(af[i], bfr[jn], acc[i][jn], 0, 0, 0);
      if (sub == 0 && j < 12) efill(j + 1);   // hidden under subs 1,2 MFMA
    }
    __syncthreads();   // E(j+1) ready; As consumed
  }

  // ---- epilogue: bias+relu, stage Y1 halves through LDS, coalesced store ----
  size_t mrow = (size_t)bL * 16384 + (size_t)y * 128;
  __hip_bfloat16* Yst = (__hip_bfloat16*)smem;   // 128*256*2 = 64KB <= 77.3KB
#pragma unroll
  for (int half = 0; half < 2; ++half) {
    if ((wv >> 2) == half) {
      __hip_bfloat16* st = Yst + (size_t)(wv & 3) * (128 * 64);
#pragma unroll
      for (int jn = 0; jn < 4; ++jn) {
        int n = wv * 64 + jn * 16 + lr;
        float bias = b1e[n];
#pragma unroll
        for (int i = 0; i < 8; ++i) {
#pragma unroll
          for (int rr = 0; rr < 4; ++rr) {
            int m = i * 16 + quad * 4 + rr;
            float z = acc[i][jn][rr] + bias;
            z = z > 0.f ? z : 0.f;
            st[m * 64 + jn * 16 + lr] = __float2bfloat16(z);
          }
        }
      }
    }
    __syncthreads();
    // copy 128 px x 256 n: 4096 b128 chunks = 512 thr x 8
#pragma unroll
    for (int it = 0; it < 8; ++it) {
      int q = it * 512 + t;
      int p2 = q >> 5, ck = q & 31;
      uint4 v = *(uint4*)(Yst + (size_t)(ck >> 3) * (128 * 64) + p2 * 64 + (ck & 7) * 8);
      *(uint4*)(Y1 + (mrow + p2) * 512 + half * 256 + ck * 8) = v;
    }
    __syncthreads();
  }
}

// ---------------------------------------------------------------------------
// gemm2: out[b][o2][p] = W2e[o2][:] * Y1[pix][:] + b2e[o2]; C[o2][pixel]
// computed directly so NCHW stores are coalesced. LDS-free (W2e L2-hot).
// ---------------------------------------------------------------------------
__global__ __launch_bounds__(256) void gemm2_kernel(
    const __hip_bfloat16* __restrict__ Y1,   // [Mpix][512]
    const __hip_bfloat16* __restrict__ W2e,  // [96][512]
    const float* __restrict__ b2e,
    float* __restrict__ out, int b0)
{
  int lane = threadIdx.x & 63, wv = threadIdx.x >> 6;
  int lr = lane & 15, quad = lane >> 4;
  int pw = blockIdx.x * 256 + wv * 64;  // wave's pixel base

  f32x4 acc[6][4];
#pragma unroll
  for (int im = 0; im < 6; ++im)
#pragma unroll
    for (int jn = 0; jn < 4; ++jn) acc[im][jn] = (f32x4){0.f, 0.f, 0.f, 0.f};

  for (int k0 = 0; k0 < 512; k0 += 32) {
    bf16x8 bfrag[4], afrag[6];
#pragma unroll
    for (int jn = 0; jn < 4; ++jn)
      bfrag[jn] = *(const bf16x8*)(Y1 + (size_t)(pw + jn * 16 + lr) * 512 + k0 + quad * 8);
#pragma unroll
    for (int im = 0; im < 6; ++im)
      afrag[im] = *(const bf16x8*)(W2e + (size_t)(im * 16 + lr) * 512 + k0 + quad * 8);
#pragma unroll
    for (int im = 0; im < 6; ++im)
#pragma unroll
      for (int jn = 0; jn < 4; ++jn)
        acc[im][jn] = __builtin_amdgcn_mfma_f32_16x16x32_bf16(afrag[im], bfrag[jn], acc[im][jn], 0, 0, 0);
  }

#pragma unroll
  for (int im = 0; im < 6; ++im) {
#pragma unroll
    for (int r = 0; r < 4; ++r) {
      int o2 = im * 16 + quad * 4 + r;
      float bias = b2e[o2];
#pragma unroll
      for (int jn = 0; jn < 4; ++jn) {
        int p = pw + jn * 16 + lr;
        out[((size_t)(b0 + (p >> 14)) * 96 + o2) * 16384 + (p & 16383)] =
            acc[im][jn][r] + bias;
      }
    }
  }
}

// ---------------------------------------------------------------------------
extern "C" void kernel_launch(void* const* d_in, const int* in_sizes, int n_in,
                              void* d_out, int out_size, void* d_ws, size_t ws_size,
                              hipStream_t stream)
{
  const float* x   = (const float*)d_in[0];
  const float* g1  = (const float*)d_in[1];
  const float* be1 = (const float*)d_in[2];
  const float* mu1 = (const float*)d_in[3];
  const float* va1 = (const float*)d_in[4];
  const float* W1  = (const float*)d_in[5];
  const float* cb1 = (const float*)d_in[6];
  const float* g2  = (const float*)d_in[7];
  const float* be2 = (const float*)d_in[8];
  const float* mu2 = (const float*)d_in[9];
  const float* va2 = (const float*)d_in[10];
  const float* W2  = (const float*)d_in[11];
  const float* cb2 = (const float*)d_in[12];
  float* out = (float*)d_out;

  // unconditional (no static guard): same work every call, capture-safe
  hipFuncSetAttribute((const void*)fused1_kernel,
                      hipFuncAttributeMaxDynamicSharedMemorySize, 77312);

  char* w = (char*)d_ws;
  __hip_bfloat16* V   = (__hip_bfloat16*)w; w += (size_t)512 * 1248 * 2;
  __hip_bfloat16* W2e = (__hip_bfloat16*)w; w += (size_t)96 * 512 * 2;
  float* b1e = (float*)w; w += 2048;
  float* b2e = (float*)w; w += 512;
  size_t fixed = (size_t)(w - (char*)d_ws);

  const size_t satB = (size_t)96 * 17028 * 4;     // per-batch SAT bytes
  const size_t yB   = (size_t)16384 * 512 * 2;    // per-batch Y1 bytes
  int nb = (ws_size >= fixed + 4 * (satB + yB) + 4096) ? 4 : 1;

  float* SAT = (float*)w; w += (size_t)nb * satB;
  w = (char*)(((uintptr_t)w + 255) & ~(uintptr_t)255);
  __hip_bfloat16* Y1 = (__hip_bfloat16*)w;

  prep1_kernel<<<512, 256, 0, stream>>>(W1, cb1, g1, be1, mu1, va1, V, b1e);
  prep2_kernel<<<96, 256, 0, stream>>>(W2, cb2, g2, be2, mu2, va2, W2e, b2e);

  for (int b0 = 0; b0 < 4; b0 += nb) {
    sat_kernel<<<nb * 96, 128, 0, stream>>>(x + (size_t)b0 * 96 * 16384, SAT);
    fused1_kernel<<<nb * 128, 512, 77312, stream>>>(SAT, V, b1e, Y1, nb);
    gemm2_kernel<<<nb * 64, 256, 0, stream>>>(Y1, W2e, b2e, out, b0);
  }
}

// Round 7
// 302.171 us; speedup vs baseline: 2.7946x; 1.0249x over previous
//
#include <hip/hip_runtime.h>
#include <hip/hip_bf16.h>
#include <cstdint>

typedef __attribute__((ext_vector_type(8))) short bf16x8;   // 8 bf16 (4 VGPRs)
typedef __attribute__((ext_vector_type(4))) float f32x4;    // MFMA C/D

#define BN_EPS 1e-5f

// ---------------------------------------------------------------------------
// prep1: fold BN1 + ring telescoping into V (box-feature weights), b1eff.
// ---------------------------------------------------------------------------
__global__ __launch_bounds__(256) void prep1_kernel(
    const float* __restrict__ W1, const float* __restrict__ cb1,
    const float* __restrict__ g1, const float* __restrict__ be1,
    const float* __restrict__ mu1, const float* __restrict__ va1,
    __hip_bfloat16* __restrict__ V, float* __restrict__ b1e)
{
  int o = blockIdx.x;
  int t = threadIdx.x;
  const float* wrow = W1 + (size_t)o * 1248;
  float acc = 0.f;
  for (int i = t; i < 1248; i += 256) {
    float s = g1[i] * rsqrtf(va1[i] + BN_EPS);
    float w = wrow[i];
    acc += w * (be1[i] - mu1[i] * s);
    float g = w * s;
    float gn = 0.f;
    if (i < 1152) {  // has a next-ring partner
      float sn = g1[i + 96] * rsqrtf(va1[i + 96] + BN_EPS);
      gn = wrow[i + 96] * sn;
    }
    V[(size_t)o * 1248 + i] = __float2bfloat16(g - gn);
  }
  for (int d = 32; d > 0; d >>= 1) acc += __shfl_down(acc, d);
  __shared__ float red[4];
  int lane = t & 63, wv = t >> 6;
  if (lane == 0) red[wv] = acc;
  __syncthreads();
  if (t == 0) b1e[o] = cb1[o] + red[0] + red[1] + red[2] + red[3];
}

// ---------------------------------------------------------------------------
// prep2: fold BN2 into W2eff, b2eff.
// ---------------------------------------------------------------------------
__global__ __launch_bounds__(256) void prep2_kernel(
    const float* __restrict__ W2, const float* __restrict__ cb2,
    const float* __restrict__ g2, const float* __restrict__ be2,
    const float* __restrict__ mu2, const float* __restrict__ va2,
    __hip_bfloat16* __restrict__ W2e, float* __restrict__ b2e)
{
  int o = blockIdx.x;
  int t = threadIdx.x;
  const float* wrow = W2 + (size_t)o * 512;
  float acc = 0.f;
  for (int j = t; j < 512; j += 256) {
    float s = g2[j] * rsqrtf(va2[j] + BN_EPS);
    float wv = wrow[j];
    acc += wv * (be2[j] - mu2[j] * s);
    W2e[(size_t)o * 512 + j] = __float2bfloat16(wv * s);
  }
  for (int d = 32; d > 0; d >>= 1) acc += __shfl_down(acc, d);
  __shared__ float red[4];
  int lane = t & 63, wv2 = t >> 6;
  if (lane == 0) red[wv2] = acc;
  __syncthreads();
  if (t == 0) b2e[o] = cb2[o] + red[0] + red[1] + red[2] + red[3];
}

// ---------------------------------------------------------------------------
// sat v2: one block per (b,c) plane. Exclusive SAT [129][132].
// ---------------------------------------------------------------------------
__global__ __launch_bounds__(128) void sat_kernel(
    const float* __restrict__ x, float* __restrict__ SAT)
{
  int plane = blockIdx.x;
  const float* xp = x + (size_t)plane * 16384;
  __shared__ float tile[16384];   // [r][granule-swizzled]
  int t = threadIdx.x;
  for (int i4 = t; i4 < 4096; i4 += 128) {
    int r = i4 >> 5;
    int g = i4 & 31;                       // granule of 4 floats
    float4 v = *(const float4*)(xp + (size_t)r * 128 + g * 4);
    *(float4*)(tile + r * 128 + ((g ^ (r & 31)) << 2)) = v;
  }
  __syncthreads();
  {  // row scan: thread = row, float4 granules with carry
    int r = t;
    float carry = 0.f;
    for (int g = 0; g < 32; ++g) {
      float* p = tile + r * 128 + ((g ^ (r & 31)) << 2);
      float4 v = *(float4*)p;
      float s0 = carry + v.x, s1 = s0 + v.y, s2 = s1 + v.z, s3 = s2 + v.w;
      float4 o; o.x = s0; o.y = s1; o.z = s2; o.w = s3;
      *(float4*)p = o;
      carry = s3;
    }
  }
  __syncthreads();
  float* Sg = SAT + (size_t)plane * 17028;  // 129*132
  Sg[t] = 0.f;                   // row 0, cols 0..127
  if (t < 4) Sg[128 + t] = 0.f;  // row 0, cols 128..131
  Sg[(t + 1) * 132] = 0.f;       // col 0, rows 1..128
  int gc = t >> 2, wc = t & 3;
  float run = 0.f;
  for (int r = 0; r < 128; ++r) {
    run += tile[r * 128 + ((gc ^ (r & 31)) << 2) + wc];
    Sg[(r + 1) * 132 + t + 1] = run;
  }
}

// ---------------------------------------------------------------------------
// fused v4: feat + gemm1 + gemm2 in one kernel. One block per image row:
// 1024 thr / 16 waves, wave tile M64xN64 (acc[4][4] = 64 acc-VGPRs ->
// ~128 total/wave -> 4 waves/SIMD; v3's M128xN64 = 256/wave = 2 waves/SIMD
// was the latency-hiding killer). Per ring j: build As[128][104] (all 96 ch),
// 3 MFMA sub-phases with efill(j+1) under sub 0. Epilogue: bias+relu ->
// Yst[128][520] bf16 in LDS (133KB dynamic, 1 block/CU - VGPR-limited
// anyway), then out = W2e x Y1^T per-block (wave = 48 o2 x 16 px), killing
// the separate gemm2 kernel and the 134MB Y1 HBM round-trip.
// ---------------------------------------------------------------------------
__global__ __launch_bounds__(1024) void fused1_kernel(
    const float* __restrict__ SAT, const __hip_bfloat16* __restrict__ V,
    const float* __restrict__ b1e, const __hip_bfloat16* __restrict__ W2e,
    const float* __restrict__ b2e, float* __restrict__ out, int nb, int b0)
{
  extern __shared__ __align__(16) char smem[];
  float* E = (float*)smem;                                   // 96*132 fp32
  __hip_bfloat16* As = (__hip_bfloat16*)(smem + 50688);      // [128][104]

  int blk = blockIdx.x;
  int rows_per_xcd = (nb * 128) >> 3;
  int r = (blk & 7) * rows_per_xcd + (blk >> 3);
  int bL = r >> 7, y = r & 127;

  int t = threadIdx.x;
  int lane = t & 63, wv = t >> 6;              // 16 waves
  int wm = wv & 1, wn = wv >> 1;               // M-half (64), N-slab (64)
  int lr = lane & 15, quad = lane >> 4;
  int px = t & 127;                            // build pixel
  int bg = t >> 7;                             // build granule 0..7

  const float* Sb = SAT + (size_t)bL * 96 * 17028;

  f32x4 acc[4][4];
#pragma unroll
  for (int i = 0; i < 4; ++i)
#pragma unroll
    for (int jn = 0; jn < 4; ++jn) acc[i][jn] = (f32x4){0.f, 0.f, 0.f, 0.f};

  // E-fill for ring j: 96 ch x 33 float4 granules = 3168 tasks (3-4 iters)
  auto efill = [&](int j) {
    int y1 = (y - j < 0) ? 0 : (y - j);
    int y2 = ((y + j > 127) ? 127 : (y + j)) + 1;
    for (int idx = t; idx < 3168; idx += 1024) {
      int cl = idx / 33;
      int ck = idx - cl * 33;
      const float* bp = Sb + (size_t)cl * 17028 + ck * 4;
      float4 a = *(const float4*)(bp + y2 * 132);
      float4 b = *(const float4*)(bp + y1 * 132);
      float4 d;
      d.x = a.x - b.x; d.y = a.y - b.y; d.z = a.z - b.z; d.w = a.w - b.w;
      *(float4*)(E + cl * 132 + ck * 4) = d;
    }
  };

  efill(0);
  __syncthreads();

  for (int j = 0; j < 13; ++j) {
    int x1 = (px - j < 0) ? 0 : (px - j);
    int x2 = ((px + j > 127) ? 127 : (px + j)) + 1;
    // build all 12 granules (96 ch): every thread does granule bg; bg<4 also 8+bg
    {
      const float* Eb = E + bg * 8 * 132;
      union { bf16x8 v; __hip_bfloat16 h[8]; } pk;
#pragma unroll
      for (int i = 0; i < 8; ++i)
        pk.h[i] = __float2bfloat16(Eb[i * 132 + x2] - Eb[i * 132 + x1]);
      *(bf16x8*)(As + px * 104 + bg * 8) = pk.v;
      if (bg < 4) {
        const float* Eb2 = E + (8 + bg) * 8 * 132;
        union { bf16x8 v; __hip_bfloat16 h[8]; } pk2;
#pragma unroll
        for (int i = 0; i < 8; ++i)
          pk2.h[i] = __float2bfloat16(Eb2[i * 132 + x2] - Eb2[i * 132 + x1]);
        *(bf16x8*)(As + px * 104 + (8 + bg) * 8) = pk2.v;
      }
    }
    __syncthreads();   // As ready; E(j) fully consumed

#pragma unroll
    for (int sub = 0; sub < 3; ++sub) {
      bf16x8 af[4], bfr[4];
#pragma unroll
      for (int i = 0; i < 4; ++i)
        af[i] = *(const bf16x8*)(As + (wm * 64 + i * 16 + lr) * 104 + sub * 32 + quad * 8);
#pragma unroll
      for (int jn = 0; jn < 4; ++jn)
        bfr[jn] = *(const bf16x8*)(V + (size_t)(wn * 64 + jn * 16 + lr) * 1248
                                   + j * 96 + sub * 32 + quad * 8);
#pragma unroll
      for (int i = 0; i < 4; ++i)
#pragma unroll
        for (int jn = 0; jn < 4; ++jn)
          acc[i][jn] = __builtin_amdgcn_mfma_f32_16x16x32_bf16(af[i], bfr[jn], acc[i][jn], 0, 0, 0);
      if (sub == 0 && j < 12) efill(j + 1);   // hidden under subs 1,2 MFMA
    }
    __syncthreads();   // E(j+1) ready; As consumed
  }

  // ---- epilogue A: bias+relu -> Yst[128][520] bf16 (row stride 260 words
  //      == 4 mod 32 -> conflict-free b128 reads below) ----
  __hip_bfloat16* Yst = (__hip_bfloat16*)smem;   // 128*520*2 = 133120 B
#pragma unroll
  for (int jn = 0; jn < 4; ++jn) {
    int n = wn * 64 + jn * 16 + lr;
    float bias = b1e[n];
#pragma unroll
    for (int i = 0; i < 4; ++i) {
#pragma unroll
      for (int rr = 0; rr < 4; ++rr) {
        int m = wm * 64 + i * 16 + quad * 4 + rr;
        float z = acc[i][jn][rr] + bias;
        z = z > 0.f ? z : 0.f;
        Yst[m * 520 + n] = __float2bfloat16(z);
      }
    }
  }
  __syncthreads();

  // ---- epilogue B: out[96][128px] = W2e[96][512] x Yst^T. 48 16x16 tiles,
  //      wave = (px-tile, m-half-of-96): 3 tiles each. ----
  int pxt = wv & 7;          // px tile
  int mh = wv >> 3;          // 0: o2 0..47, 1: o2 48..95
  f32x4 acc2[3];
#pragma unroll
  for (int im = 0; im < 3; ++im) acc2[im] = (f32x4){0.f, 0.f, 0.f, 0.f};

  for (int k2 = 0; k2 < 512; k2 += 32) {
    bf16x8 bfr2 = *(const bf16x8*)(Yst + (pxt * 16 + lr) * 520 + k2 + quad * 8);
#pragma unroll
    for (int im = 0; im < 3; ++im) {
      bf16x8 afr2 = *(const bf16x8*)(W2e + (size_t)(mh * 48 + im * 16 + lr) * 512
                                     + k2 + quad * 8);
      acc2[im] = __builtin_amdgcn_mfma_f32_16x16x32_bf16(afr2, bfr2, acc2[im], 0, 0, 0);
    }
  }

  size_t obase = ((size_t)(b0 + bL) * 96) * 16384 + (size_t)y * 128 + pxt * 16 + lr;
#pragma unroll
  for (int im = 0; im < 3; ++im) {
#pragma unroll
    for (int rr = 0; rr < 4; ++rr) {
      int o2 = mh * 48 + im * 16 + quad * 4 + rr;
      out[obase + (size_t)o2 * 16384] = acc2[im][rr] + b2e[o2];
    }
  }
}

// ---------------------------------------------------------------------------
extern "C" void kernel_launch(void* const* d_in, const int* in_sizes, int n_in,
                              void* d_out, int out_size, void* d_ws, size_t ws_size,
                              hipStream_t stream)
{
  const float* x   = (const float*)d_in[0];
  const float* g1  = (const float*)d_in[1];
  const float* be1 = (const float*)d_in[2];
  const float* mu1 = (const float*)d_in[3];
  const float* va1 = (const float*)d_in[4];
  const float* W1  = (const float*)d_in[5];
  const float* cb1 = (const float*)d_in[6];
  const float* g2  = (const float*)d_in[7];
  const float* be2 = (const float*)d_in[8];
  const float* mu2 = (const float*)d_in[9];
  const float* va2 = (const float*)d_in[10];
  const float* W2  = (const float*)d_in[11];
  const float* cb2 = (const float*)d_in[12];
  float* out = (float*)d_out;

  hipFuncSetAttribute((const void*)fused1_kernel,
                      hipFuncAttributeMaxDynamicSharedMemorySize, 133120);

  char* w = (char*)d_ws;
  __hip_bfloat16* V   = (__hip_bfloat16*)w; w += (size_t)512 * 1248 * 2;
  __hip_bfloat16* W2e = (__hip_bfloat16*)w; w += (size_t)96 * 512 * 2;
  float* b1e = (float*)w; w += 2048;
  float* b2e = (float*)w; w += 512;
  size_t fixed = (size_t)(w - (char*)d_ws);

  const size_t satB = (size_t)96 * 17028 * 4;     // per-batch SAT bytes
  int nb = (ws_size >= fixed + 4 * satB + 4096) ? 4 : 1;

  float* SAT = (float*)w;

  prep1_kernel<<<512, 256, 0, stream>>>(W1, cb1, g1, be1, mu1, va1, V, b1e);
  prep2_kernel<<<96, 256, 0, stream>>>(W2, cb2, g2, be2, mu2, va2, W2e, b2e);

  for (int b0 = 0; b0 < 4; b0 += nb) {
    sat_kernel<<<nb * 96, 128, 0, stream>>>(x + (size_t)b0 * 96 * 16384, SAT);
    fused1_kernel<<<nb * 128, 1024, 133120, stream>>>(SAT, V, b1e, W2e, b2e, out, nb, b0);
  }
}